// Round 3
// baseline (563.456 us; speedup 1.0000x reference)
//
#include <hip/hip_runtime.h>

#define HW 4096
#define CAP 262144u

typedef short bf16x8 __attribute__((ext_vector_type(8)));
typedef float f32x4 __attribute__((ext_vector_type(4)));

__device__ __forceinline__ ushort f2bf_rne(float f) {
    unsigned u = __float_as_uint(f);
    return (ushort)((u + 0x7FFFu + ((u >> 16) & 1u)) >> 16);
}

// ---------------------------------------------------------------------------
// init: zero the candidate counter and the per-(b,n) best-key array
// (d_ws is re-poisoned 0xAA before every launch).
// ---------------------------------------------------------------------------
__global__ __launch_bounds__(256) void init_kernel(
    unsigned long long* __restrict__ best, unsigned* __restrict__ cnt)
{
    int i = blockIdx.x * 256 + threadIdx.x;   // 16384
    best[i] = 0ull;
    if (i == 0) cnt[0] = 0u;
}

// ---------------------------------------------------------------------------
// Kernel 1: 1x1-conv projection.
// Outputs:
//   Qt/Pt fp32 [b][n][128]  (transposed, for exact rescore; p L2-normalized,
//                            q unnormalized -- argmax invariant to +scale)
//   Qpk/Ppk bf16 in MFMA fragment order [b][nt][ks][lane][j]:
//       elem = X[c = ks*32 + (lane>>4)*8 + j][n = nt*16 + (lane&15)]
//   qnorm[b][n] = ||q_n||_2 (for the candidate margin)
// ---------------------------------------------------------------------------
__global__ __launch_bounds__(256) void proj_kernel(
    const float* __restrict__ Fq, const float* __restrict__ Fp,
    const float* __restrict__ Wm, const float* __restrict__ bias,
    float* __restrict__ Qt, float* __restrict__ Pt,
    ushort* __restrict__ Qpk, ushort* __restrict__ Ppk,
    float* __restrict__ qnorm)
{
    __shared__ float Xs[64][64];
    __shared__ float sq[4][64];

    const int tid = threadIdx.x;
    const int z = blockIdx.z;                  // 0: q, 1: p
    const float* __restrict__ X = z ? Fp : Fq;
    const int b  = blockIdx.y;
    const int n0 = blockIdx.x * 64;
    const int n  = tid & 63;
    const int og = __builtin_amdgcn_readfirstlane(tid >> 6);

    float acc[32];
    #pragma unroll
    for (int j = 0; j < 32; ++j) acc[j] = 0.f;

    for (int cc = 0; cc < 4; ++cc) {
        #pragma unroll
        for (int i = 0; i < 16; ++i) {
            int idx = tid + i * 256;
            int r = idx >> 6, nn = idx & 63;
            Xs[r][nn] = X[(size_t)(b * 256 + cc * 64 + r) * HW + n0 + nn];
        }
        __syncthreads();
        for (int r = 0; r < 64; ++r) {
            float x = Xs[r][n];
            int c = cc * 64 + r;
            #pragma unroll
            for (int j = 0; j < 32; ++j)
                acc[j] += Wm[(og * 32 + j) * 256 + c] * x;   // scalar W loads
        }
        __syncthreads();
    }

    #pragma unroll
    for (int j = 0; j < 32; ++j) acc[j] += bias[og * 32 + j];

    float ssq = 0.f;
    #pragma unroll
    for (int j = 0; j < 32; ++j) ssq += acc[j] * acc[j];
    sq[og][n] = ssq;
    __syncthreads();
    float tot = sq[0][n] + sq[1][n] + sq[2][n] + sq[3][n];
    if (z) {
        float s = 1.0f / sqrtf(tot);
        #pragma unroll
        for (int j = 0; j < 32; ++j) acc[j] *= s;
    } else if (og == 0) {
        qnorm[b * HW + n0 + n] = sqrtf(tot);
    }

    // fp32 transposed output (32 contiguous floats per thread)
    {
        float* __restrict__ T = z ? Pt : Qt;
        size_t tb = ((size_t)b * HW + n0 + n) * 128 + og * 32;
        #pragma unroll
        for (int j = 0; j < 32; j += 4)
            *(float4*)&T[tb + j] = make_float4(acc[j], acc[j+1], acc[j+2], acc[j+3]);
    }
    // bf16 fragment-order pack (4 x 16B stores per thread)
    {
        ushort* __restrict__ PK = z ? Ppk : Qpk;
        const int nt = (n0 + n) >> 4;
        const int nl = n & 15;
        #pragma unroll
        for (int g = 0; g < 4; ++g) {
            ushort u[8];
            #pragma unroll
            for (int k = 0; k < 8; ++k) u[k] = f2bf_rne(acc[g * 8 + k]);
            size_t pk = ((((size_t)b * 256 + nt) * 4 + og) * 64 + (nl + 16 * g)) * 8;
            uint4 w;
            w.x = (unsigned)u[0] | ((unsigned)u[1] << 16);
            w.y = (unsigned)u[2] | ((unsigned)u[3] << 16);
            w.z = (unsigned)u[4] | ((unsigned)u[5] << 16);
            w.w = (unsigned)u[6] | ((unsigned)u[7] << 16);
            *(uint4*)&PK[pk] = w;
        }
    }
}

// ---------------------------------------------------------------------------
// MFMA sim pass.  Block: 256 thr = 4 waves, n-tile 256 (64/wave), m-range 512
// (blockIdx.z of 8), chunks of 128 m through 32 KB LDS.  A-frags in registers.
// 16x16x32 bf16 MFMA, D: col(m)=lane&15, row(n)=(lane>>4)*4+reg.
// PASS 1: per-(n, ms) max -> Vmax.   PASS 2: append m with s >= thr[n].
// Both passes run the identical MFMA sequence -> bitwise-identical s.
// ---------------------------------------------------------------------------
template<int PASS>
__global__ __launch_bounds__(256, 2) void sim_pass_kernel(
    const ushort* __restrict__ Qpk, const ushort* __restrict__ Ppk,
    const float* __restrict__ thr,
    float* __restrict__ Vmax,
    unsigned* __restrict__ cnt, unsigned* __restrict__ cand)
{
    __shared__ ushort Bs[16384];   // 32 KB: 8 m-tiles x 4 ks x 64 lanes x 8

    const int tid  = threadIdx.x;
    const int lane = tid & 63;
    const int w    = tid >> 6;
    const int nblk = blockIdx.x;   // 16
    const int b    = blockIdx.y;   // 4
    const int ms   = blockIdx.z;   // 8 -> m in [ms*512, ms*512+512)

    // A fragments: 4 n-tiles x 4 k-steps, 16 B/lane each (64 VGPRs)
    bf16x8 afrag[4][4];
    {
        const uint4* Qp4 = (const uint4*)Qpk;
        #pragma unroll
        for (int ntl = 0; ntl < 4; ++ntl) {
            int nt = nblk * 16 + w * 4 + ntl;
            #pragma unroll
            for (int ks = 0; ks < 4; ++ks) {
                uint4 t = Qp4[(((size_t)b * 256 + nt) * 4 + ks) * 64 + lane];
                union { uint4 u; bf16x8 v; } cv; cv.u = t;
                afrag[ntl][ks] = cv.v;
            }
        }
    }

    float bestv[16];
    float thrreg[16];
    if (PASS == 1) {
        #pragma unroll
        for (int i = 0; i < 16; ++i) bestv[i] = -1e30f;
    } else {
        #pragma unroll
        for (int ntl = 0; ntl < 4; ++ntl)
            #pragma unroll
            for (int r = 0; r < 4; ++r)
                thrreg[ntl * 4 + r] =
                    thr[b * HW + nblk * 256 + w * 64 + ntl * 16 + (lane >> 4) * 4 + r];
    }

    const size_t pbase = ((size_t)b * 256 + ms * 32) * 2048;  // elems

    for (int ch = 0; ch < 4; ++ch) {
        __syncthreads();
        // stage 32 KB contiguous (pack order == LDS order, lane-linear)
        const uint4* src = (const uint4*)(Ppk + pbase + (size_t)ch * 8 * 2048);
        uint4* dstl = (uint4*)Bs;
        #pragma unroll
        for (int it = 0; it < 8; ++it) {
            int f = it * 256 + tid;
            dstl[f] = src[f];
        }
        __syncthreads();

        for (int mtl = 0; mtl < 8; ++mtl) {
            bf16x8 bfrag[4];
            #pragma unroll
            for (int ks = 0; ks < 4; ++ks)
                bfrag[ks] = *(const bf16x8*)&Bs[(((mtl * 4) + ks) * 64 + lane) * 8];

            #pragma unroll
            for (int ntl = 0; ntl < 4; ++ntl) {
                f32x4 acc = {0.f, 0.f, 0.f, 0.f};
                #pragma unroll
                for (int ks = 0; ks < 4; ++ks)
                    acc = __builtin_amdgcn_mfma_f32_16x16x32_bf16(
                              afrag[ntl][ks], bfrag[ks], acc, 0, 0, 0);

                if (PASS == 1) {
                    #pragma unroll
                    for (int r = 0; r < 4; ++r)
                        bestv[ntl * 4 + r] = fmaxf(bestv[ntl * 4 + r], acc[r]);
                } else {
                    const int m = ms * 512 + ch * 128 + mtl * 16 + (lane & 15);
                    #pragma unroll
                    for (int r = 0; r < 4; ++r) {
                        if (acc[r] >= thrreg[ntl * 4 + r]) {
                            int nrow = nblk * 256 + w * 64 + ntl * 16 + (lane >> 4) * 4 + r;
                            unsigned idx = atomicAdd(cnt, 1u);
                            if (idx < CAP)
                                cand[idx] = ((unsigned)b << 24) | ((unsigned)nrow << 12) | (unsigned)m;
                        }
                    }
                }
            }
        }
    }

    if (PASS == 1) {
        #pragma unroll
        for (int i = 0; i < 16; ++i) {
            float v = bestv[i];
            #pragma unroll
            for (int d = 1; d < 16; d <<= 1)
                v = fmaxf(v, __shfl_xor(v, d, 64));
            if ((lane & 15) == 0) {
                int nrow = nblk * 256 + w * 64 + (i >> 2) * 16 + (lane >> 4) * 4 + (i & 3);
                Vmax[((size_t)b * HW + nrow) * 8 + ms] = v;
            }
        }
    }
}

// ---------------------------------------------------------------------------
// threshold: thr[n] = max_s Vmax[n][s] - (0.016*||q_n|| + 1e-6)
// margin bound: |s_bf16 - s_fp32| <= (2*2^-8 + 2^-16)*||q||*||p||(1+2^-8)
//               + 128*2^-24*||q|| < 0.00787*||q||  ->  2*delta < 0.016*||q||
// ---------------------------------------------------------------------------
__global__ __launch_bounds__(256) void thresh_kernel(
    const float* __restrict__ Vmax, const float* __restrict__ qnorm,
    float* __restrict__ thr)
{
    int i = blockIdx.x * 256 + threadIdx.x;   // 16384
    float g = -1e30f;
    #pragma unroll
    for (int s = 0; s < 8; ++s) g = fmaxf(g, Vmax[(size_t)i * 8 + s]);
    thr[i] = g - (0.016f * qnorm[i] + 1e-6f);
}

// ---------------------------------------------------------------------------
// exact fp32 rescore of candidates; sequential-c fma chain (same summation
// structure that matched np argmax in rounds 1-2).  Merge per (b,n) via
// packed u64 atomicMax: (orderedbits(v) << 32) | (4095 - m)  ->  max value,
// ties broken toward smallest m (np.argmax first occurrence).
// ---------------------------------------------------------------------------
__global__ __launch_bounds__(256) void rescore_kernel(
    const float* __restrict__ Qt, const float* __restrict__ Pt,
    const unsigned* __restrict__ cand, const unsigned* __restrict__ cnt,
    unsigned long long* __restrict__ best)
{
    unsigned total = cnt[0];
    if (total > CAP) total = CAP;
    for (unsigned i = blockIdx.x * 256 + threadIdx.x; i < total; i += gridDim.x * 256) {
        unsigned c = cand[i];
        int m = c & 0xFFF, n = (c >> 12) & 0xFFF, b = c >> 24;
        const float* __restrict__ q = Qt + ((size_t)b * HW + n) * 128;
        const float* __restrict__ p = Pt + ((size_t)b * HW + m) * 128;
        float acc = 0.f;
        for (int k = 0; k < 128; ++k) acc += q[k] * p[k];
        unsigned u = __float_as_uint(acc);
        unsigned kk = (u & 0x80000000u) ? ~u : (u | 0x80000000u);
        unsigned long long key = ((unsigned long long)kk << 32) | (unsigned)(4095 - m);
        atomicMax(&best[(size_t)b * HW + n], key);
    }
}

// ---------------------------------------------------------------------------
// gather: out[b][c][n] = Fp[b][c][m(n)];  stage each 16 KB Fp row in LDS,
// random reads hit LDS instead of L2 lines (33.6 MB total vs ~270 MB).
// ---------------------------------------------------------------------------
__global__ __launch_bounds__(256) void gather_kernel(
    const float* __restrict__ Fp, const unsigned long long* __restrict__ best,
    float* __restrict__ out)
{
    __shared__ float row[4096];
    const int blk = blockIdx.x;      // 1024 = 4b x 256c
    const int c = blk & 255;
    const int b = blk >> 8;
    const int tid = threadIdx.x;

    const float* __restrict__ src = Fp + ((size_t)b * 256 + c) * HW;
    #pragma unroll
    for (int it = 0; it < 4; ++it) {
        int f = it * 256 + tid;
        *(float4*)&row[f * 4] = *(const float4*)&src[f * 4];
    }
    __syncthreads();

    float* __restrict__ dst = out + ((size_t)b * 256 + c) * HW;
    #pragma unroll
    for (int it = 0; it < 16; ++it) {
        int n = it * 256 + tid;
        int m = 4095 - (int)(best[(size_t)b * HW + n] & 0xFFFull);
        dst[n] = row[m];
    }
}

extern "C" void kernel_launch(void* const* d_in, const int* in_sizes, int n_in,
                              void* d_out, int out_size, void* d_ws, size_t ws_size,
                              hipStream_t stream) {
    const float* Fq   = (const float*)d_in[0];
    const float* Fp   = (const float*)d_in[1];
    const float* Wm   = (const float*)d_in[2];
    const float* bias = (const float*)d_in[3];
    float* out = (float*)d_out;

    // workspace layout (~25.8 MB):
    char* base = (char*)d_ws;
    float*  Qt    = (float*)(base);                               // 8 MB
    float*  Pt    = (float*)(base + (8u << 20));                  // 8 MB
    ushort* Qpk   = (ushort*)(base + (16u << 20));                // 4 MB
    ushort* Ppk   = (ushort*)(base + (20u << 20));                // 4 MB
    char* x = base + (24u << 20);
    float*  qnorm = (float*)x;              x += 65536;           // 64 KB
    float*  Vmax  = (float*)x;              x += 524288;          // 512 KB
    float*  thr   = (float*)x;              x += 65536;           // 64 KB
    unsigned long long* best = (unsigned long long*)x; x += 131072; // 128 KB
    unsigned* cnt  = (unsigned*)x;          x += 16;
    unsigned* cand = (unsigned*)x;                                 // 1 MB

    init_kernel<<<64, 256, 0, stream>>>(best, cnt);
    proj_kernel<<<dim3(64, 4, 2), 256, 0, stream>>>(Fq, Fp, Wm, bias,
                                                    Qt, Pt, Qpk, Ppk, qnorm);
    sim_pass_kernel<1><<<dim3(16, 4, 8), 256, 0, stream>>>(Qpk, Ppk, nullptr,
                                                           Vmax, nullptr, nullptr);
    thresh_kernel<<<64, 256, 0, stream>>>(Vmax, qnorm, thr);
    sim_pass_kernel<2><<<dim3(16, 4, 8), 256, 0, stream>>>(Qpk, Ppk, thr,
                                                           nullptr, cnt, cand);
    rescore_kernel<<<128, 256, 0, stream>>>(Qt, Pt, cand, cnt, best);
    gather_kernel<<<1024, 256, 0, stream>>>(Fp, best, out);
}

// Round 4
// 560.406 us; speedup vs baseline: 1.0054x; 1.0054x over previous
//
#include <hip/hip_runtime.h>

#define HW 4096
#define CAP 262144u

typedef short bf16x8 __attribute__((ext_vector_type(8)));
typedef float f32x4 __attribute__((ext_vector_type(4)));

__device__ __forceinline__ ushort f2bf_rne(float f) {
    unsigned u = __float_as_uint(f);
    return (ushort)((u + 0x7FFFu + ((u >> 16) & 1u)) >> 16);
}

// ---------------------------------------------------------------------------
// init: zero the candidate counter and the per-(b,n) best-key array.
// ---------------------------------------------------------------------------
__global__ __launch_bounds__(256) void init_kernel(
    unsigned long long* __restrict__ best, unsigned* __restrict__ cnt)
{
    int i = blockIdx.x * 256 + threadIdx.x;   // 16384
    best[i] = 0ull;
    if (i == 0) cnt[0] = 0u;
}

// ---------------------------------------------------------------------------
// Kernel 1: 1x1-conv projection (unchanged from round 3).
// Outputs: Qt/Pt fp32 [b][n][128] (rescore), Qpk/Ppk bf16 in MFMA fragment
// order [b][nt][ks][lane][j] with elem = X[c=ks*32+(lane>>4)*8+j][n=nt*16+(lane&15)],
// qnorm[b][n] = ||q_n||.
// ---------------------------------------------------------------------------
__global__ __launch_bounds__(256) void proj_kernel(
    const float* __restrict__ Fq, const float* __restrict__ Fp,
    const float* __restrict__ Wm, const float* __restrict__ bias,
    float* __restrict__ Qt, float* __restrict__ Pt,
    ushort* __restrict__ Qpk, ushort* __restrict__ Ppk,
    float* __restrict__ qnorm)
{
    __shared__ float Xs[64][64];
    __shared__ float sq[4][64];

    const int tid = threadIdx.x;
    const int z = blockIdx.z;
    const float* __restrict__ X = z ? Fp : Fq;
    const int b  = blockIdx.y;
    const int n0 = blockIdx.x * 64;
    const int n  = tid & 63;
    const int og = __builtin_amdgcn_readfirstlane(tid >> 6);

    float acc[32];
    #pragma unroll
    for (int j = 0; j < 32; ++j) acc[j] = 0.f;

    for (int cc = 0; cc < 4; ++cc) {
        #pragma unroll
        for (int i = 0; i < 16; ++i) {
            int idx = tid + i * 256;
            int r = idx >> 6, nn = idx & 63;
            Xs[r][nn] = X[(size_t)(b * 256 + cc * 64 + r) * HW + n0 + nn];
        }
        __syncthreads();
        for (int r = 0; r < 64; ++r) {
            float x = Xs[r][n];
            int c = cc * 64 + r;
            #pragma unroll
            for (int j = 0; j < 32; ++j)
                acc[j] += Wm[(og * 32 + j) * 256 + c] * x;
        }
        __syncthreads();
    }

    #pragma unroll
    for (int j = 0; j < 32; ++j) acc[j] += bias[og * 32 + j];

    float ssq = 0.f;
    #pragma unroll
    for (int j = 0; j < 32; ++j) ssq += acc[j] * acc[j];
    sq[og][n] = ssq;
    __syncthreads();
    float tot = sq[0][n] + sq[1][n] + sq[2][n] + sq[3][n];
    if (z) {
        float s = 1.0f / sqrtf(tot);
        #pragma unroll
        for (int j = 0; j < 32; ++j) acc[j] *= s;
    } else if (og == 0) {
        qnorm[b * HW + n0 + n] = sqrtf(tot);
    }

    {
        float* __restrict__ T = z ? Pt : Qt;
        size_t tb = ((size_t)b * HW + n0 + n) * 128 + og * 32;
        #pragma unroll
        for (int j = 0; j < 32; j += 4)
            *(float4*)&T[tb + j] = make_float4(acc[j], acc[j+1], acc[j+2], acc[j+3]);
    }
    {
        ushort* __restrict__ PK = z ? Ppk : Qpk;
        const int nt = (n0 + n) >> 4;
        const int nl = n & 15;
        #pragma unroll
        for (int g = 0; g < 4; ++g) {
            ushort u[8];
            #pragma unroll
            for (int k = 0; k < 8; ++k) u[k] = f2bf_rne(acc[g * 8 + k]);
            size_t pk = ((((size_t)b * 256 + nt) * 4 + og) * 64 + (nl + 16 * g)) * 8;
            uint4 w;
            w.x = (unsigned)u[0] | ((unsigned)u[1] << 16);
            w.y = (unsigned)u[2] | ((unsigned)u[3] << 16);
            w.z = (unsigned)u[4] | ((unsigned)u[5] << 16);
            w.w = (unsigned)u[6] | ((unsigned)u[7] << 16);
            *(uint4*)&PK[pk] = w;
        }
    }
}

// ---------------------------------------------------------------------------
// MFMA sim pass, restructured: BOTH operands live in LDS so the register
// allocator can never rematerialize global loads into the inner loop
// (the round-3 pathology: VGPR=72 < live set, waves 98% idle on global
// latency).  Worst-case remat now re-reads LDS (12 cyc) -- harmless.
//
// Grid (32, 4, 4): block = 128 n x 1024 m, one b.  LDS: Qs 32 KB (staged
// once) + Bs 32 KB per 128-m chunk = 64 KB -> 2 blocks/CU.
// Wave w owns n-tiles {w*2, w*2+1}; per chunk loops 8 m-tiles, bfrag[4]
// (16 VGPR) reused across both n-tiles; afrag[2][4] = 32 VGPR.
// D mapping (verified by round-3 absmax=0): n_row=(lane>>4)*4+reg, m=lane&15.
// PASS 1: per-(n, ms) max -> Vmax.  PASS 2: emit m with s >= thr[n]
// (wave-aggregated atomics).  Identical MFMA chain order in both passes
// -> bitwise-identical s.
// ---------------------------------------------------------------------------
template<int PASS>
__global__ __launch_bounds__(256, 2) void sim_pass_kernel(
    const ushort* __restrict__ Qpk, const ushort* __restrict__ Ppk,
    const float* __restrict__ thr,
    float* __restrict__ Vmax,
    unsigned* __restrict__ cnt, unsigned* __restrict__ cand)
{
    __shared__ ushort Qs[16384];   // 32 KB: 8 nt x 4 ks x 64 lanes x 8
    __shared__ ushort Bs[16384];   // 32 KB: 8 mt x 4 ks x 64 lanes x 8

    const int tid  = threadIdx.x;
    const int lane = tid & 63;
    const int w    = tid >> 6;
    const int nb   = blockIdx.x;   // 32 -> n in [nb*128, nb*128+128)
    const int b    = blockIdx.y;   // 4
    const int ms   = blockIdx.z;   // 4 -> m in [ms*1024, ms*1024+1024)

    // stage Q tile once (contiguous: pack order == LDS order)
    {
        const uint4* src = (const uint4*)(Qpk + ((size_t)b * 256 + nb * 8) * 2048);
        uint4* dst = (uint4*)Qs;
        #pragma unroll
        for (int it = 0; it < 8; ++it) dst[it * 256 + tid] = src[it * 256 + tid];
    }
    __syncthreads();

    // A fragments for this wave's 2 n-tiles (32 VGPR; backed by LDS)
    bf16x8 afrag[2][4];
    #pragma unroll
    for (int ntl = 0; ntl < 2; ++ntl)
        #pragma unroll
        for (int ks = 0; ks < 4; ++ks)
            afrag[ntl][ks] = *(const bf16x8*)&Qs[(((w * 2 + ntl) * 4 + ks) * 64 + lane) * 8];

    float bestv[8];
    float thrreg[8];
    if (PASS == 1) {
        #pragma unroll
        for (int i = 0; i < 8; ++i) bestv[i] = -1e30f;
    } else {
        #pragma unroll
        for (int ntl = 0; ntl < 2; ++ntl)
            #pragma unroll
            for (int r = 0; r < 4; ++r)
                thrreg[ntl * 4 + r] =
                    thr[b * HW + nb * 128 + (w * 2 + ntl) * 16 + (lane >> 4) * 4 + r];
    }

    for (int ch = 0; ch < 8; ++ch) {
        __syncthreads();   // protect prior chunk's Bs reads
        {
            const uint4* src = (const uint4*)(Ppk +
                ((size_t)b * 256 + ms * 64 + ch * 8) * 2048);
            uint4* dst = (uint4*)Bs;
            #pragma unroll
            for (int it = 0; it < 8; ++it) dst[it * 256 + tid] = src[it * 256 + tid];
        }
        __syncthreads();

        for (int mt = 0; mt < 8; ++mt) {
            bf16x8 bfrag[4];
            #pragma unroll
            for (int ks = 0; ks < 4; ++ks)
                bfrag[ks] = *(const bf16x8*)&Bs[((mt * 4 + ks) * 64 + lane) * 8];

            #pragma unroll
            for (int ntl = 0; ntl < 2; ++ntl) {
                f32x4 acc = {0.f, 0.f, 0.f, 0.f};
                #pragma unroll
                for (int ks = 0; ks < 4; ++ks)
                    acc = __builtin_amdgcn_mfma_f32_16x16x32_bf16(
                              afrag[ntl][ks], bfrag[ks], acc, 0, 0, 0);

                if (PASS == 1) {
                    #pragma unroll
                    for (int r = 0; r < 4; ++r)
                        bestv[ntl * 4 + r] = fmaxf(bestv[ntl * 4 + r], acc[r]);
                } else {
                    const int m = ms * 1024 + ch * 128 + mt * 16 + (lane & 15);
                    #pragma unroll
                    for (int r = 0; r < 4; ++r) {
                        bool cond = (acc[r] >= thrreg[ntl * 4 + r]);
                        unsigned long long mask = __ballot(cond);
                        if (cond) {
                            int leader = __ffsll((long long)mask) - 1;
                            unsigned base = 0;
                            if (lane == leader)
                                base = atomicAdd(cnt, (unsigned)__popcll(mask));
                            base = __shfl(base, leader, 64);
                            unsigned off = base +
                                (unsigned)__popcll(mask & ((1ull << lane) - 1ull));
                            int nrow = nb * 128 + (w * 2 + ntl) * 16 + (lane >> 4) * 4 + r;
                            if (off < CAP)
                                cand[off] = ((unsigned)b << 24) | ((unsigned)nrow << 12) | (unsigned)m;
                        }
                    }
                }
            }
        }
    }

    if (PASS == 1) {
        #pragma unroll
        for (int i = 0; i < 8; ++i) {
            float v = bestv[i];
            #pragma unroll
            for (int d = 1; d < 16; d <<= 1)
                v = fmaxf(v, __shfl_xor(v, d, 64));
            if ((lane & 15) == 0) {
                int nrow = nb * 128 + (w * 2 + (i >> 2)) * 16 + (lane >> 4) * 4 + (i & 3);
                Vmax[((size_t)b * HW + nrow) * 4 + ms] = v;
            }
        }
    }
}

// ---------------------------------------------------------------------------
// threshold: thr[n] = max_s Vmax[n][s] - (0.016*||q_n|| + 1e-6)
// margin bound: |s_bf16 - s_fp32| < 0.00787*||q||  ->  2*delta < 0.016*||q||
// ---------------------------------------------------------------------------
__global__ __launch_bounds__(256) void thresh_kernel(
    const float* __restrict__ Vmax, const float* __restrict__ qnorm,
    float* __restrict__ thr)
{
    int i = blockIdx.x * 256 + threadIdx.x;   // 16384
    float g = -1e30f;
    #pragma unroll
    for (int s = 0; s < 4; ++s) g = fmaxf(g, Vmax[(size_t)i * 4 + s]);
    thr[i] = g - (0.016f * qnorm[i] + 1e-6f);
}

// ---------------------------------------------------------------------------
// exact fp32 rescore of candidates (sequential-c fma chain -- the summation
// structure that matched np argmax in rounds 1-2).  Merge per (b,n) via
// packed u64 atomicMax: (orderedbits(v) << 32) | (4095 - m).
// ---------------------------------------------------------------------------
__global__ __launch_bounds__(256) void rescore_kernel(
    const float* __restrict__ Qt, const float* __restrict__ Pt,
    const unsigned* __restrict__ cand, const unsigned* __restrict__ cnt,
    unsigned long long* __restrict__ best)
{
    unsigned total = cnt[0];
    if (total > CAP) total = CAP;
    for (unsigned i = blockIdx.x * 256 + threadIdx.x; i < total; i += gridDim.x * 256) {
        unsigned c = cand[i];
        int m = c & 0xFFF, n = (c >> 12) & 0xFFF, b = c >> 24;
        const float* __restrict__ q = Qt + ((size_t)b * HW + n) * 128;
        const float* __restrict__ p = Pt + ((size_t)b * HW + m) * 128;
        float acc = 0.f;
        for (int k = 0; k < 128; ++k) acc += q[k] * p[k];
        unsigned u = __float_as_uint(acc);
        unsigned kk = (u & 0x80000000u) ? ~u : (u | 0x80000000u);
        unsigned long long key = ((unsigned long long)kk << 32) | (unsigned)(4095 - m);
        atomicMax(&best[(size_t)b * HW + n], key);
    }
}

// ---------------------------------------------------------------------------
// gather: out[b][c][n] = Fp[b][c][m(n)]; stage each 16 KB Fp row in LDS.
// ---------------------------------------------------------------------------
__global__ __launch_bounds__(256) void gather_kernel(
    const float* __restrict__ Fp, const unsigned long long* __restrict__ best,
    float* __restrict__ out)
{
    __shared__ float row[4096];
    const int blk = blockIdx.x;      // 1024 = 4b x 256c
    const int c = blk & 255;
    const int b = blk >> 8;
    const int tid = threadIdx.x;

    const float* __restrict__ src = Fp + ((size_t)b * 256 + c) * HW;
    #pragma unroll
    for (int it = 0; it < 4; ++it) {
        int f = it * 256 + tid;
        *(float4*)&row[f * 4] = *(const float4*)&src[f * 4];
    }
    __syncthreads();

    float* __restrict__ dst = out + ((size_t)b * 256 + c) * HW;
    #pragma unroll
    for (int it = 0; it < 16; ++it) {
        int n = it * 256 + tid;
        int m = 4095 - (int)(best[(size_t)b * HW + n] & 0xFFFull);
        dst[n] = row[m];
    }
}

extern "C" void kernel_launch(void* const* d_in, const int* in_sizes, int n_in,
                              void* d_out, int out_size, void* d_ws, size_t ws_size,
                              hipStream_t stream) {
    const float* Fq   = (const float*)d_in[0];
    const float* Fp   = (const float*)d_in[1];
    const float* Wm   = (const float*)d_in[2];
    const float* bias = (const float*)d_in[3];
    float* out = (float*)d_out;

    char* base = (char*)d_ws;
    float*  Qt    = (float*)(base);                               // 8 MB
    float*  Pt    = (float*)(base + (8u << 20));                  // 8 MB
    ushort* Qpk   = (ushort*)(base + (16u << 20));                // 4 MB
    ushort* Ppk   = (ushort*)(base + (20u << 20));                // 4 MB
    char* x = base + (24u << 20);
    float*  qnorm = (float*)x;              x += 65536;           // 64 KB
    float*  Vmax  = (float*)x;              x += 262144;          // 256 KB
    float*  thr   = (float*)x;              x += 65536;           // 64 KB
    unsigned long long* best = (unsigned long long*)x; x += 131072; // 128 KB
    unsigned* cnt  = (unsigned*)x;          x += 16;
    unsigned* cand = (unsigned*)x;                                 // 1 MB

    init_kernel<<<64, 256, 0, stream>>>(best, cnt);
    proj_kernel<<<dim3(64, 4, 2), 256, 0, stream>>>(Fq, Fp, Wm, bias,
                                                    Qt, Pt, Qpk, Ppk, qnorm);
    sim_pass_kernel<1><<<dim3(32, 4, 4), 256, 0, stream>>>(Qpk, Ppk, nullptr,
                                                           Vmax, nullptr, nullptr);
    thresh_kernel<<<64, 256, 0, stream>>>(Vmax, qnorm, thr);
    sim_pass_kernel<2><<<dim3(32, 4, 4), 256, 0, stream>>>(Qpk, Ppk, thr,
                                                           nullptr, cnt, cand);
    rescore_kernel<<<128, 256, 0, stream>>>(Qt, Pt, cand, cnt, best);
    gather_kernel<<<1024, 256, 0, stream>>>(Fp, best, out);
}